// Round 17
// baseline (851.495 us; speedup 1.0000x reference)
//
#include <hip/hip_runtime.h>
#include <hip/hip_bf16.h>
#include <cstdint>
#include <math.h>

#define N_TOK 8192
#define D_DIM 1024
#define F_DIM 4096
#define NE 8
#define CAP 8192
#define MAXT 72    // max sum_e ceil(cnt_e/256) = 71, padded

typedef __attribute__((ext_vector_type(8))) short short8;
typedef __attribute__((ext_vector_type(4))) short short4v;
typedef __attribute__((ext_vector_type(4))) float f32x4;

__device__ __forceinline__ short f2bf(float f) {
  __bf16 b = (__bf16)f;
  return *(short*)&b;
}
__device__ __forceinline__ float bf2f(short u) {
  union { unsigned int i; float f; } c;
  c.i = ((unsigned int)(unsigned short)u) << 16;
  return c.f;
}
__device__ __forceinline__ void gload(const void* g, void* l) {
  __builtin_amdgcn_global_load_lds(
      (const __attribute__((address_space(1))) uint32_t*)g,
      (__attribute__((address_space(3))) uint32_t*)l, 16, 0, 0);
}

// ---------------- gating + fused X->bf16 ------------------------------------
__global__ __launch_bounds__(256) void gate_kernel(
    const float* __restrict__ X, const float* __restrict__ Wg,
    const float* __restrict__ bg, int* __restrict__ cnt,
    int* __restrict__ bucket, float* __restrict__ pairw,
    unsigned short* __restrict__ Xb)
{
  const int token = blockIdx.x;
  const int tid = threadIdx.x;
  const float4* x4 = (const float4*)(X + (size_t)token * D_DIM);
  const float4* wg4 = (const float4*)Wg;
  float part[NE];
#pragma unroll
  for (int e = 0; e < NE; ++e) part[e] = 0.f;
  const float4 xv = x4[tid];
#pragma unroll
  for (int e = 0; e < NE; ++e) {
    const float4 wv = wg4[e * (D_DIM / 4) + tid];
    part[e] = fmaf(xv.x, wv.x, fmaf(xv.y, wv.y, fmaf(xv.z, wv.z, fmaf(xv.w, wv.w, part[e]))));
  }
  short4v o;
  o.x = f2bf(xv.x); o.y = f2bf(xv.y); o.z = f2bf(xv.z); o.w = f2bf(xv.w);
  ((short4v*)(Xb + (size_t)token * D_DIM))[tid] = o;

#pragma unroll
  for (int e = 0; e < NE; ++e) {
#pragma unroll
    for (int off = 32; off > 0; off >>= 1) part[e] += __shfl_down(part[e], off);
  }
  __shared__ float wsum[4][NE];
  const int wave = tid >> 6;
  if ((tid & 63) == 0) {
#pragma unroll
    for (int e = 0; e < NE; ++e) wsum[wave][e] = part[e];
  }
  __syncthreads();
  if (tid == 0) {
    float lg[NE];
#pragma unroll
    for (int e = 0; e < NE; ++e)
      lg[e] = wsum[0][e] + wsum[1][e] + wsum[2][e] + wsum[3][e] + bg[e];
    int e0 = 0;
#pragma unroll
    for (int e = 1; e < NE; ++e) if (lg[e] > lg[e0]) e0 = e;     // jax tie-break: lower idx
    int e1 = (e0 == 0) ? 1 : 0;
#pragma unroll
    for (int e = 0; e < NE; ++e) if (e != e0 && lg[e] > lg[e1]) e1 = e;
    float p1 = expf(lg[e1] - lg[e0]);            // p0 = 1; softmax denom cancels
    float inv = 1.f / (1.f + p1);
    pairw[token * 2]     = inv;
    pairw[token * 2 + 1] = p1 * inv;
    int pos0 = atomicAdd(&cnt[e0], 1);
    bucket[e0 * CAP + pos0] = token * 2;
    int pos1 = atomicAdd(&cnt[e1], 1);
    bucket[e1 * CAP + pos1] = token * 2 + 1;
  }
}

// ---------------- prefix sums + pair->slot map (one launch) -----------------
__global__ __launch_bounds__(256) void prefix_fill_kernel(
    const int* __restrict__ cnt, int* __restrict__ expoff,
    int* __restrict__ toff, const int* __restrict__ bucket,
    int* __restrict__ pairslot)
{
  __shared__ int soff[NE];
  if (threadIdx.x == 0) {
    int s = 0, t = 0;
#pragma unroll
    for (int e = 0; e < NE; ++e) {
      expoff[e] = s; soff[e] = s;
      toff[e] = t;
      s += cnt[e];
      t += (cnt[e] + 255) >> 8;
    }
    toff[NE] = t;
  }
  __syncthreads();
  for (int e = 0; e < NE; ++e) {
    const int n = cnt[e], off = soff[e];
    for (int p = threadIdx.x; p < n; p += 256)
      pairslot[bucket[e * CAP + p]] = off + p;
  }
}

// ---------------- both weight transposes in ONE launch ----------------------
__global__ __launch_bounds__(256) void transpose_both_kernel(
    const float* __restrict__ W1, const float* __restrict__ W2,
    unsigned short* __restrict__ W1t, unsigned short* __restrict__ W2t)
{
  __shared__ float tileT[64][68];
  const int z = blockIdx.z;
  const bool is1 = (z < NE);
  const int ez = is1 ? z : z - NE;
  const int R = is1 ? D_DIM : F_DIM;
  const int C = is1 ? F_DIM : D_DIM;
  const float* src = (is1 ? W1 : W2) + (size_t)ez * D_DIM * F_DIM;
  unsigned short* dst = (is1 ? W1t : W2t) + (size_t)ez * D_DIM * F_DIM;
  const int c0 = (is1 ? blockIdx.x : blockIdx.y) * 64;
  const int r0 = (is1 ? blockIdx.y : blockIdx.x) * 64;
  const int tid = threadIdx.x;
  const int cx = tid & 15;
  const int ry = tid >> 4;
#pragma unroll
  for (int i = 0; i < 4; ++i) {
    const int row = ry + i * 16;
    const float4 v = *(const float4*)(src + (size_t)(r0 + row) * C + c0 + cx * 4);
    tileT[cx * 4 + 0][row] = v.x;
    tileT[cx * 4 + 1][row] = v.y;
    tileT[cx * 4 + 2][row] = v.z;
    tileT[cx * 4 + 3][row] = v.w;
  }
  __syncthreads();
#pragma unroll
  for (int i = 0; i < 4; ++i) {
    const int cc = ry + i * 16;
    const float4 v = *(const float4*)(&tileT[cc][cx * 4]);
    short4v o;
    o.x = f2bf(v.x); o.y = f2bf(v.y); o.z = f2bf(v.z); o.w = f2bf(v.w);
    *(short4v*)(dst + (size_t)(c0 + cc) * R + r0 + cx * 4) = o;
  }
}

// ---------------- grouped expert GEMM: 256x256, K=32 halves, ring-4 ---------
// R15 core (280 us, 0 conflicts) with READ-EARLY rotation: per half H
//   lgkmcnt(0) -> 32 MFMA (frags read during H-1) -> stage(H+3) ->
//   vmcnt(8) [own H+1 landed] -> s_barrier [ALL waves' H+1 landed] ->
//   issue frags(H+1) ds_reads (NOT waited).
// The 96 KB/half LDS read burst now overlaps the barrier skew + next MFMA
// window instead of serializing between barrier and MFMA (R15's stall).
// WAR ledger: stage(H+3) -> slot (H-1)&3, whose reads completed at top of
// H-1 (>=1 barrier earlier); reads(H+1) gated by vmcnt+barrier; frag regs
// reused after MFMA consumes them. Tail: vmcnt 8 -> 4 -> 0, reads/stages
// predicated. Flight: 2-3 halves of DMA always outstanding.
template<int LAYER>
__global__ __launch_bounds__(512) void moe_gemm(
    const unsigned short* __restrict__ Abase,
    const unsigned short* __restrict__ Bt,
    const float* __restrict__ bias,
    const int* __restrict__ cnt,
    const int* __restrict__ expoff,
    const int* __restrict__ toff,
    const int* __restrict__ bucket,
    unsigned short* __restrict__ OutA,
    unsigned short* __restrict__ OutB)
{
  constexpr int BM = 256, BN = 256;
  constexpr int KDIM = (LAYER == 1) ? D_DIM : F_DIM;
  constexpr int NDIM = (LAYER == 1) ? F_DIM : D_DIM;
  constexpr int KSPAN = (LAYER == 1) ? KDIM : (KDIM / 2);  // per-block K range
  constexpr int HALVES = KSPAN / 32;                       // 32 or 64

  const int q = gridDim.x >> 3;
  const int g = (blockIdx.x & 7) * q + (blockIdx.x >> 3);
  const int cc = g / MAXT;                 // L1: ntile; L2: (ntile<<1)|split
  const int mt = g % MAXT;
  if (mt >= toff[NE]) return;
  int e = 0;
  while (mt >= toff[e + 1]) ++e;
  const int mtile = mt - toff[e];
  const int cnt_e = cnt[e];
  const int eoff = expoff[e];
  const int ntile = (LAYER == 1) ? cc : (cc >> 1);
  const int split = (LAYER == 1) ? 0 : (cc & 1);
  const int kbase = split * KSPAN;

  __shared__ __align__(16) char Alds[4 * 16384];   // 64 KiB ring-4
  __shared__ __align__(16) char Blds[4 * 16384];   // 64 KiB ring-4
  __shared__ int rowpair[BM];

  const int tid = threadIdx.x;
  const int lane = tid & 63;
  const int l15 = lane & 15, lhi = lane >> 4;
  const int wid = tid >> 6;
  const int uw = __builtin_amdgcn_readfirstlane(wid);
  const int wm = wid >> 2, wn = wid & 3;           // 2M x 4N

  if (LAYER == 1) {
    if (tid < BM) {
      int pos = mtile * BM + tid;
      rowpair[tid] = (pos < cnt_e) ? bucket[e * CAP + pos] : -1;
    }
    __syncthreads();
  }

  // staging: half = 1024 chunks of 16 B; thread owns ci = i*512+tid (i=0,1);
  // r = ci>>2, c = ci&3; source chunk sc = c ^ ((r>>1)&3) (inverse swizzle)
  // so linear DMA dest (i*8192 + uw*1024 + lane*16) == swizzled read image.
  const unsigned short* a_src[2];
  const unsigned short* b_src[2];
#pragma unroll
  for (int i = 0; i < 2; ++i) {
    int ci = i * 512 + tid;
    int r = ci >> 2, c = ci & 3;
    int sc = c ^ ((r >> 1) & 3);
    size_t arow;
    if (LAYER == 1) {
      int pair = rowpair[r];
      arow = (pair < 0) ? 0 : (size_t)(pair >> 1);
    } else {
      arow = (size_t)(eoff + mtile * BM + r);      // contiguous slot rows
    }
    a_src[i] = Abase + arow * KDIM + kbase + sc * 8;
    b_src[i] = Bt + (size_t)e * NDIM * KDIM +
               (size_t)(ntile * BN + r) * KDIM + kbase + sc * 8;
  }

  auto stage = [&](int h) {
    const int s = h & 3;
#pragma unroll
    for (int i = 0; i < 2; ++i)
      gload(a_src[i] + h * 32, &Alds[0] + s * 16384 + i * 8192 + uw * 1024);
#pragma unroll
    for (int i = 0; i < 2; ++i)
      gload(b_src[i] + h * 32, &Blds[0] + s * 16384 + i * 8192 + uw * 1024);
  };

  f32x4 acc[8][4];
#pragma unroll
  for (int m = 0; m < 8; ++m)
#pragma unroll
    for (int n = 0; n < 4; ++n) acc[m][n] = (f32x4){0.f, 0.f, 0.f, 0.f};

  short8 bfr[4], af[8];
  auto read_frags = [&](int h) {
    const char* aSlot = &Alds[0] + (h & 3) * 16384;
    const char* bSlot = &Blds[0] + (h & 3) * 16384;
#pragma unroll
    for (int n = 0; n < 4; ++n) {
      const int row = wn * 64 + n * 16 + l15;
      bfr[n] = *(const short8*)(bSlot + row * 64 + ((lhi ^ ((row >> 1) & 3)) << 4));
    }
#pragma unroll
    for (int m = 0; m < 8; ++m) {
      const int row = wm * 128 + m * 16 + l15;
      af[m] = *(const short8*)(aSlot + row * 64 + ((lhi ^ ((row >> 1) & 3)) << 4));
    }
  };

  // prologue: stage h0,h1,h2 (12 insts); wait h0,h1; read frags(0) early.
  stage(0); stage(1); stage(2);
  asm volatile("s_waitcnt vmcnt(4)" ::: "memory");
  __builtin_amdgcn_sched_barrier(0);
  __builtin_amdgcn_s_barrier();
  __builtin_amdgcn_sched_barrier(0);
  read_frags(0);

  for (int H = 0; H < HALVES; ++H) {
    asm volatile("s_waitcnt lgkmcnt(0)" ::: "memory");   // frags(H) ready
    __builtin_amdgcn_sched_barrier(0);
    __builtin_amdgcn_s_setprio(1);
#pragma unroll
    for (int m = 0; m < 8; ++m)
#pragma unroll
      for (int n = 0; n < 4; ++n)
        acc[m][n] = __builtin_amdgcn_mfma_f32_16x16x32_bf16(af[m], bfr[n], acc[m][n], 0, 0, 0);
    __builtin_amdgcn_s_setprio(0);
    if (H + 3 < HALVES) stage(H + 3);                    // refills slot (H-1)&3
    if (H + 1 < HALVES) {
      if (H + 3 < HALVES)      asm volatile("s_waitcnt vmcnt(8)" ::: "memory");
      else if (H + 2 < HALVES) asm volatile("s_waitcnt vmcnt(4)" ::: "memory");
      else                     asm volatile("s_waitcnt vmcnt(0)" ::: "memory");
      __builtin_amdgcn_sched_barrier(0);
      __builtin_amdgcn_s_barrier();                      // all waves: H+1 in LDS
      __builtin_amdgcn_sched_barrier(0);
      read_frags(H + 1);                                 // issued, waited next iter
    }
  }

  // epilogue: C/D layout col = lane&15, row = (lane>>4)*4 + j
#pragma unroll
  for (int m = 0; m < 8; ++m) {
#pragma unroll
    for (int j = 0; j < 4; ++j) {
      const int row = wm * 128 + m * 16 + lhi * 4 + j;
      if (mtile * BM + row >= cnt_e) continue;
      const size_t slot = (size_t)(eoff + mtile * BM + row);
#pragma unroll
      for (int n = 0; n < 4; ++n) {
        const int col = ntile * BN + wn * 64 + n * 16 + l15;
        if (LAYER == 1) {
          float val = acc[m][n][j] + bias[e * NDIM + col];
          float gl = 0.5f * val * (1.f + erff(val * 0.70710678118654752f));
          OutA[slot * F_DIM + col] = (unsigned short)f2bf(gl);
        } else {
          float val = acc[m][n][j] + (split == 0 ? bias[e * NDIM + col] : 0.f);
          unsigned short* dst = (split == 0) ? OutA : OutB;
          dst[slot * D_DIM + col] = (unsigned short)f2bf(val);
        }
      }
    }
  }
}

// ---------------- combine: out[t] = w0*(yA+yB)[s0] + w1*(yA+yB)[s1] ---------
__global__ __launch_bounds__(256) void combine_kernel(
    const unsigned short* __restrict__ ybufA, const unsigned short* __restrict__ ybufB,
    const float* __restrict__ pairw, const int* __restrict__ pairslot,
    float* __restrict__ out)
{
  const int t = blockIdx.x;
  const int tid = threadIdx.x;
  const float w0 = pairw[t * 2], w1 = pairw[t * 2 + 1];
  const int s0 = pairslot[t * 2], s1 = pairslot[t * 2 + 1];
  const short4v a0 = ((const short4v*)(ybufA + (size_t)s0 * D_DIM))[tid];
  const short4v b0 = ((const short4v*)(ybufB + (size_t)s0 * D_DIM))[tid];
  const short4v a1 = ((const short4v*)(ybufA + (size_t)s1 * D_DIM))[tid];
  const short4v b1 = ((const short4v*)(ybufB + (size_t)s1 * D_DIM))[tid];
  float4 o;
  o.x = w0 * (bf2f(a0.x) + bf2f(b0.x)) + w1 * (bf2f(a1.x) + bf2f(b1.x));
  o.y = w0 * (bf2f(a0.y) + bf2f(b0.y)) + w1 * (bf2f(a1.y) + bf2f(b1.y));
  o.z = w0 * (bf2f(a0.z) + bf2f(b0.z)) + w1 * (bf2f(a1.z) + bf2f(b1.z));
  o.w = w0 * (bf2f(a0.w) + bf2f(b0.w)) + w1 * (bf2f(a1.w) + bf2f(b1.w));
  ((float4*)(out + (size_t)t * D_DIM))[tid] = o;
}

// ---------------- launch ----------------------------------------------------
extern "C" void kernel_launch(void* const* d_in, const int* in_sizes, int n_in,
                              void* d_out, int out_size, void* d_ws, size_t ws_size,
                              hipStream_t stream)
{
  const float* X  = (const float*)d_in[0];
  const float* Wg = (const float*)d_in[1];
  const float* bg = (const float*)d_in[2];
  const float* W1 = (const float*)d_in[3];
  const float* b1 = (const float*)d_in[4];
  const float* W2 = (const float*)d_in[5];
  const float* b2 = (const float*)d_in[6];
  float* out = (float*)d_out;

  char* ws = (char*)d_ws;
  size_t off = 0;
  auto alloc = [&](size_t sz) {
    size_t o = off;
    off = (off + sz + 255) & ~(size_t)255;
    return o;
  };
  int*            cnt      = (int*)(ws + alloc(NE * sizeof(int)));
  int*            expoff   = (int*)(ws + alloc(NE * sizeof(int)));
  int*            toff     = (int*)(ws + alloc((NE + 1) * sizeof(int)));
  int*            bucket   = (int*)(ws + alloc((size_t)NE * CAP * sizeof(int)));
  float*          pairw    = (float*)(ws + alloc((size_t)N_TOK * 2 * sizeof(float)));
  int*            pairslot = (int*)(ws + alloc((size_t)N_TOK * 2 * sizeof(int)));
  unsigned short* Xb       = (unsigned short*)(ws + alloc((size_t)N_TOK * D_DIM * 2));
  unsigned short* W1t      = (unsigned short*)(ws + alloc((size_t)NE * D_DIM * F_DIM * 2));
  unsigned short* W2t      = (unsigned short*)(ws + alloc((size_t)NE * D_DIM * F_DIM * 2));
  unsigned short* hmid     = (unsigned short*)(ws + alloc((size_t)(N_TOK * 2 + 256) * F_DIM * 2));
  unsigned short* ybufB    = (unsigned short*)(ws + alloc((size_t)(N_TOK * 2 + 256) * D_DIM * 2));
  unsigned short* ybufA    = W1t;   // W1t dead after GEMM1

  hipMemsetAsync(cnt, 0, NE * sizeof(int), stream);

  gate_kernel<<<N_TOK, 256, 0, stream>>>(X, Wg, bg, cnt, bucket, pairw, Xb);
  transpose_both_kernel<<<dim3(64, 16, 2 * NE), 256, 0, stream>>>(W1, W2, W1t, W2t);
  prefix_fill_kernel<<<1, 256, 0, stream>>>(cnt, expoff, toff, bucket, pairslot);

  moe_gemm<1><<<MAXT * (F_DIM / 256), 512, 0, stream>>>(   // 1152 blocks (%8==0)
      Xb, W1t, b1, cnt, expoff, toff, bucket, hmid, nullptr);
  moe_gemm<2><<<MAXT * (D_DIM / 256) * 2, 512, 0, stream>>>( // 576 blocks (%8==0)
      hmid, W2t, b2, cnt, expoff, toff, bucket, ybufA, ybufB);
  combine_kernel<<<N_TOK, 256, 0, stream>>>(ybufA, ybufB, pairw, pairslot, out);
}

// Round 18
// 724.370 us; speedup vs baseline: 1.1755x; 1.1755x over previous
//
#include <hip/hip_runtime.h>
#include <hip/hip_bf16.h>
#include <cstdint>
#include <math.h>

#define N_TOK 8192
#define D_DIM 1024
#define F_DIM 4096
#define NE 8
#define CAP 8192
#define MAXT 72    // max sum_e ceil(cnt_e/256) = 71, padded

typedef __attribute__((ext_vector_type(8))) short short8;
typedef __attribute__((ext_vector_type(4))) short short4v;
typedef __attribute__((ext_vector_type(4))) float f32x4;

__device__ __forceinline__ short f2bf(float f) {
  __bf16 b = (__bf16)f;
  return *(short*)&b;
}
__device__ __forceinline__ float bf2f(short u) {
  union { unsigned int i; float f; } c;
  c.i = ((unsigned int)(unsigned short)u) << 16;
  return c.f;
}
__device__ __forceinline__ void gload(const void* g, void* l) {
  __builtin_amdgcn_global_load_lds(
      (const __attribute__((address_space(1))) uint32_t*)g,
      (__attribute__((address_space(3))) uint32_t*)l, 16, 0, 0);
}

// ---------------- gating + fused X->bf16 ------------------------------------
__global__ __launch_bounds__(256) void gate_kernel(
    const float* __restrict__ X, const float* __restrict__ Wg,
    const float* __restrict__ bg, int* __restrict__ cnt,
    int* __restrict__ bucket, float* __restrict__ pairw,
    unsigned short* __restrict__ Xb)
{
  const int token = blockIdx.x;
  const int tid = threadIdx.x;
  const float4* x4 = (const float4*)(X + (size_t)token * D_DIM);
  const float4* wg4 = (const float4*)Wg;
  float part[NE];
#pragma unroll
  for (int e = 0; e < NE; ++e) part[e] = 0.f;
  const float4 xv = x4[tid];
#pragma unroll
  for (int e = 0; e < NE; ++e) {
    const float4 wv = wg4[e * (D_DIM / 4) + tid];
    part[e] = fmaf(xv.x, wv.x, fmaf(xv.y, wv.y, fmaf(xv.z, wv.z, fmaf(xv.w, wv.w, part[e]))));
  }
  short4v o;
  o.x = f2bf(xv.x); o.y = f2bf(xv.y); o.z = f2bf(xv.z); o.w = f2bf(xv.w);
  ((short4v*)(Xb + (size_t)token * D_DIM))[tid] = o;

#pragma unroll
  for (int e = 0; e < NE; ++e) {
#pragma unroll
    for (int off = 32; off > 0; off >>= 1) part[e] += __shfl_down(part[e], off);
  }
  __shared__ float wsum[4][NE];
  const int wave = tid >> 6;
  if ((tid & 63) == 0) {
#pragma unroll
    for (int e = 0; e < NE; ++e) wsum[wave][e] = part[e];
  }
  __syncthreads();
  if (tid == 0) {
    float lg[NE];
#pragma unroll
    for (int e = 0; e < NE; ++e)
      lg[e] = wsum[0][e] + wsum[1][e] + wsum[2][e] + wsum[3][e] + bg[e];
    int e0 = 0;
#pragma unroll
    for (int e = 1; e < NE; ++e) if (lg[e] > lg[e0]) e0 = e;     // jax tie-break: lower idx
    int e1 = (e0 == 0) ? 1 : 0;
#pragma unroll
    for (int e = 0; e < NE; ++e) if (e != e0 && lg[e] > lg[e1]) e1 = e;
    float p1 = expf(lg[e1] - lg[e0]);            // p0 = 1; softmax denom cancels
    float inv = 1.f / (1.f + p1);
    pairw[token * 2]     = inv;
    pairw[token * 2 + 1] = p1 * inv;
    int pos0 = atomicAdd(&cnt[e0], 1);
    bucket[e0 * CAP + pos0] = token * 2;
    int pos1 = atomicAdd(&cnt[e1], 1);
    bucket[e1 * CAP + pos1] = token * 2 + 1;
  }
}

// ---------------- prefix sums + pair->slot map (one launch) -----------------
__global__ __launch_bounds__(256) void prefix_fill_kernel(
    const int* __restrict__ cnt, int* __restrict__ expoff,
    int* __restrict__ toff, const int* __restrict__ bucket,
    int* __restrict__ pairslot)
{
  __shared__ int soff[NE];
  if (threadIdx.x == 0) {
    int s = 0, t = 0;
#pragma unroll
    for (int e = 0; e < NE; ++e) {
      expoff[e] = s; soff[e] = s;
      toff[e] = t;
      s += cnt[e];
      t += (cnt[e] + 255) >> 8;
    }
    toff[NE] = t;
  }
  __syncthreads();
  for (int e = 0; e < NE; ++e) {
    const int n = cnt[e], off = soff[e];
    for (int p = threadIdx.x; p < n; p += 256)
      pairslot[bucket[e * CAP + p]] = off + p;
  }
}

// ---------------- both weight transposes in ONE launch ----------------------
__global__ __launch_bounds__(256) void transpose_both_kernel(
    const float* __restrict__ W1, const float* __restrict__ W2,
    unsigned short* __restrict__ W1t, unsigned short* __restrict__ W2t)
{
  __shared__ float tileT[64][68];
  const int z = blockIdx.z;
  const bool is1 = (z < NE);
  const int ez = is1 ? z : z - NE;
  const int R = is1 ? D_DIM : F_DIM;
  const int C = is1 ? F_DIM : D_DIM;
  const float* src = (is1 ? W1 : W2) + (size_t)ez * D_DIM * F_DIM;
  unsigned short* dst = (is1 ? W1t : W2t) + (size_t)ez * D_DIM * F_DIM;
  const int c0 = (is1 ? blockIdx.x : blockIdx.y) * 64;
  const int r0 = (is1 ? blockIdx.y : blockIdx.x) * 64;
  const int tid = threadIdx.x;
  const int cx = tid & 15;
  const int ry = tid >> 4;
#pragma unroll
  for (int i = 0; i < 4; ++i) {
    const int row = ry + i * 16;
    const float4 v = *(const float4*)(src + (size_t)(r0 + row) * C + c0 + cx * 4);
    tileT[cx * 4 + 0][row] = v.x;
    tileT[cx * 4 + 1][row] = v.y;
    tileT[cx * 4 + 2][row] = v.z;
    tileT[cx * 4 + 3][row] = v.w;
  }
  __syncthreads();
#pragma unroll
  for (int i = 0; i < 4; ++i) {
    const int cc = ry + i * 16;
    const float4 v = *(const float4*)(&tileT[cc][cx * 4]);
    short4v o;
    o.x = f2bf(v.x); o.y = f2bf(v.y); o.z = f2bf(v.z); o.w = f2bf(v.w);
    *(short4v*)(dst + (size_t)(c0 + cc) * R + r0 + cx * 4) = o;
  }
}

// ---------------- grouped expert GEMM: 256x256, 16 waves, ring-3 ------------
// R15 schedule rescaled to 1024 threads / 16 waves (4M x 4N, wave = 64x64,
// acc[4][4] = 64 VGPR -> ~110 total <= 128 -> 16 waves/CU resident). The DMA
// staging rate scales with resident waves (R7/R9: 8 waves-as-2-blocks = 9.5
// B/cyc vs R15 8-wave-1-block = 7); 16 waves is the untested cell.
// LDS: A/B halves = 256 rows x 64 B = 16 KB, ring-3 (96 KB). Swizzle
// c ^ ((r>>1)&3) (R15-proven, 0 conflicts). Per half H: vmcnt(2) [H landed;
// H+1 in flight] + barrier -> read frags (8 ds_read/wave) -> stage(H+2)
// (2 insts/thread, refills slot (H-1)%3, safe: all waves finished H-1's
// reads before H's barrier) -> lgkmcnt(0) -> setprio + 16 MFMA.
// Tail: vmcnt(2)->(0), stages predicated.
template<int LAYER>
__global__ __launch_bounds__(1024, 4) void moe_gemm(
    const unsigned short* __restrict__ Abase,
    const unsigned short* __restrict__ Bt,
    const float* __restrict__ bias,
    const int* __restrict__ cnt,
    const int* __restrict__ expoff,
    const int* __restrict__ toff,
    const int* __restrict__ bucket,
    unsigned short* __restrict__ OutA,
    unsigned short* __restrict__ OutB)
{
  constexpr int BM = 256, BN = 256;
  constexpr int KDIM = (LAYER == 1) ? D_DIM : F_DIM;
  constexpr int NDIM = (LAYER == 1) ? F_DIM : D_DIM;
  constexpr int KSPAN = (LAYER == 1) ? KDIM : (KDIM / 2);  // per-block K range
  constexpr int HALVES = KSPAN / 32;                       // 32 or 64

  const int q = gridDim.x >> 3;
  const int g = (blockIdx.x & 7) * q + (blockIdx.x >> 3);
  const int cc = g / MAXT;                 // L1: ntile; L2: (ntile<<1)|split
  const int mt = g % MAXT;
  if (mt >= toff[NE]) return;
  int e = 0;
  while (mt >= toff[e + 1]) ++e;
  const int mtile = mt - toff[e];
  const int cnt_e = cnt[e];
  const int eoff = expoff[e];
  const int ntile = (LAYER == 1) ? cc : (cc >> 1);
  const int split = (LAYER == 1) ? 0 : (cc & 1);
  const int kbase = split * KSPAN;

  __shared__ __align__(16) char Alds[3 * 16384];   // 48 KiB ring-3
  __shared__ __align__(16) char Blds[3 * 16384];   // 48 KiB ring-3
  __shared__ int rowpair[BM];

  const int tid = threadIdx.x;
  const int lane = tid & 63;
  const int l15 = lane & 15, lhi = lane >> 4;
  const int wid = tid >> 6;
  const int uw = __builtin_amdgcn_readfirstlane(wid);
  const int wm = wid >> 2, wn = wid & 3;           // 4M x 4N waves

  if (LAYER == 1) {
    if (tid < BM) {
      int pos = mtile * BM + tid;
      rowpair[tid] = (pos < cnt_e) ? bucket[e * CAP + pos] : -1;
    }
    __syncthreads();
  }

  // staging: half = 1024 chunks of 16 B; thread owns chunk ci = tid for each
  // operand; r = ci>>2, c = ci&3; source chunk sc = c ^ ((r>>1)&3) (inverse
  // swizzle) so linear DMA dest (uw*1024 + lane*16) == swizzled read image.
  const unsigned short* a_src;
  const unsigned short* b_src;
  {
    int ci = tid;
    int r = ci >> 2, c = ci & 3;
    int sc = c ^ ((r >> 1) & 3);
    size_t arow;
    if (LAYER == 1) {
      int pair = rowpair[r];
      arow = (pair < 0) ? 0 : (size_t)(pair >> 1);
    } else {
      arow = (size_t)(eoff + mtile * BM + r);      // contiguous slot rows
    }
    a_src = Abase + arow * KDIM + kbase + sc * 8;
    b_src = Bt + (size_t)e * NDIM * KDIM +
            (size_t)(ntile * BN + r) * KDIM + kbase + sc * 8;
  }

  auto stage = [&](int h) {
    const int s = h % 3;
    gload(a_src + h * 32, &Alds[0] + s * 16384 + uw * 1024);
    gload(b_src + h * 32, &Blds[0] + s * 16384 + uw * 1024);
  };

  f32x4 acc[4][4];
#pragma unroll
  for (int m = 0; m < 4; ++m)
#pragma unroll
    for (int n = 0; n < 4; ++n) acc[m][n] = (f32x4){0.f, 0.f, 0.f, 0.f};

  stage(0); stage(1);                      // 4 insts/thread outstanding

  for (int H = 0; H < HALVES; ++H) {
    if (H + 1 < HALVES) asm volatile("s_waitcnt vmcnt(2)" ::: "memory");
    else                asm volatile("s_waitcnt vmcnt(0)" ::: "memory");
    __builtin_amdgcn_sched_barrier(0);
    __builtin_amdgcn_s_barrier();

    const char* aSlot = &Alds[0] + (H % 3) * 16384;
    const char* bSlot = &Blds[0] + (H % 3) * 16384;
    short8 bfr[4], af[4];
#pragma unroll
    for (int n = 0; n < 4; ++n) {
      const int row = wn * 64 + n * 16 + l15;
      bfr[n] = *(const short8*)(bSlot + row * 64 + ((lhi ^ ((row >> 1) & 3)) << 4));
    }
#pragma unroll
    for (int m = 0; m < 4; ++m) {
      const int row = wm * 64 + m * 16 + l15;
      af[m] = *(const short8*)(aSlot + row * 64 + ((lhi ^ ((row >> 1) & 3)) << 4));
    }
    if (H + 2 < HALVES) stage(H + 2);      // refills slot (H-1)%3
    asm volatile("s_waitcnt lgkmcnt(0)" ::: "memory");
    __builtin_amdgcn_sched_barrier(0);
    __builtin_amdgcn_s_setprio(1);
#pragma unroll
    for (int m = 0; m < 4; ++m)
#pragma unroll
      for (int n = 0; n < 4; ++n)
        acc[m][n] = __builtin_amdgcn_mfma_f32_16x16x32_bf16(af[m], bfr[n], acc[m][n], 0, 0, 0);
    __builtin_amdgcn_s_setprio(0);
  }

  // epilogue: C/D layout col = lane&15, row = (lane>>4)*4 + j
#pragma unroll
  for (int m = 0; m < 4; ++m) {
#pragma unroll
    for (int j = 0; j < 4; ++j) {
      const int row = wm * 64 + m * 16 + lhi * 4 + j;
      if (mtile * BM + row >= cnt_e) continue;
      const size_t slot = (size_t)(eoff + mtile * BM + row);
#pragma unroll
      for (int n = 0; n < 4; ++n) {
        const int col = ntile * BN + wn * 64 + n * 16 + l15;
        if (LAYER == 1) {
          float val = acc[m][n][j] + bias[e * NDIM + col];
          float gl = 0.5f * val * (1.f + erff(val * 0.70710678118654752f));
          OutA[slot * F_DIM + col] = (unsigned short)f2bf(gl);
        } else {
          float val = acc[m][n][j] + (split == 0 ? bias[e * NDIM + col] : 0.f);
          unsigned short* dst = (split == 0) ? OutA : OutB;
          dst[slot * D_DIM + col] = (unsigned short)f2bf(val);
        }
      }
    }
  }
}

// ---------------- combine: out[t] = w0*(yA+yB)[s0] + w1*(yA+yB)[s1] ---------
__global__ __launch_bounds__(256) void combine_kernel(
    const unsigned short* __restrict__ ybufA, const unsigned short* __restrict__ ybufB,
    const float* __restrict__ pairw, const int* __restrict__ pairslot,
    float* __restrict__ out)
{
  const int t = blockIdx.x;
  const int tid = threadIdx.x;
  const float w0 = pairw[t * 2], w1 = pairw[t * 2 + 1];
  const int s0 = pairslot[t * 2], s1 = pairslot[t * 2 + 1];
  const short4v a0 = ((const short4v*)(ybufA + (size_t)s0 * D_DIM))[tid];
  const short4v b0 = ((const short4v*)(ybufB + (size_t)s0 * D_DIM))[tid];
  const short4v a1 = ((const short4v*)(ybufA + (size_t)s1 * D_DIM))[tid];
  const short4v b1 = ((const short4v*)(ybufB + (size_t)s1 * D_DIM))[tid];
  float4 o;
  o.x = w0 * (bf2f(a0.x) + bf2f(b0.x)) + w1 * (bf2f(a1.x) + bf2f(b1.x));
  o.y = w0 * (bf2f(a0.y) + bf2f(b0.y)) + w1 * (bf2f(a1.y) + bf2f(b1.y));
  o.z = w0 * (bf2f(a0.z) + bf2f(b0.z)) + w1 * (bf2f(a1.z) + bf2f(b1.z));
  o.w = w0 * (bf2f(a0.w) + bf2f(b0.w)) + w1 * (bf2f(a1.w) + bf2f(b1.w));
  ((float4*)(out + (size_t)t * D_DIM))[tid] = o;
}

// ---------------- launch ----------------------------------------------------
extern "C" void kernel_launch(void* const* d_in, const int* in_sizes, int n_in,
                              void* d_out, int out_size, void* d_ws, size_t ws_size,
                              hipStream_t stream)
{
  const float* X  = (const float*)d_in[0];
  const float* Wg = (const float*)d_in[1];
  const float* bg = (const float*)d_in[2];
  const float* W1 = (const float*)d_in[3];
  const float* b1 = (const float*)d_in[4];
  const float* W2 = (const float*)d_in[5];
  const float* b2 = (const float*)d_in[6];
  float* out = (float*)d_out;

  char* ws = (char*)d_ws;
  size_t off = 0;
  auto alloc = [&](size_t sz) {
    size_t o = off;
    off = (off + sz + 255) & ~(size_t)255;
    return o;
  };
  int*            cnt      = (int*)(ws + alloc(NE * sizeof(int)));
  int*            expoff   = (int*)(ws + alloc(NE * sizeof(int)));
  int*            toff     = (int*)(ws + alloc((NE + 1) * sizeof(int)));
  int*            bucket   = (int*)(ws + alloc((size_t)NE * CAP * sizeof(int)));
  float*          pairw    = (float*)(ws + alloc((size_t)N_TOK * 2 * sizeof(float)));
  int*            pairslot = (int*)(ws + alloc((size_t)N_TOK * 2 * sizeof(int)));
  unsigned short* Xb       = (unsigned short*)(ws + alloc((size_t)N_TOK * D_DIM * 2));
  unsigned short* W1t      = (unsigned short*)(ws + alloc((size_t)NE * D_DIM * F_DIM * 2));
  unsigned short* W2t      = (unsigned short*)(ws + alloc((size_t)NE * D_DIM * F_DIM * 2));
  unsigned short* hmid     = (unsigned short*)(ws + alloc((size_t)(N_TOK * 2 + 256) * F_DIM * 2));
  unsigned short* ybufB    = (unsigned short*)(ws + alloc((size_t)(N_TOK * 2 + 256) * D_DIM * 2));
  unsigned short* ybufA    = W1t;   // W1t dead after GEMM1

  hipMemsetAsync(cnt, 0, NE * sizeof(int), stream);

  gate_kernel<<<N_TOK, 256, 0, stream>>>(X, Wg, bg, cnt, bucket, pairw, Xb);
  transpose_both_kernel<<<dim3(64, 16, 2 * NE), 256, 0, stream>>>(W1, W2, W1t, W2t);
  prefix_fill_kernel<<<1, 256, 0, stream>>>(cnt, expoff, toff, bucket, pairslot);

  moe_gemm<1><<<MAXT * (F_DIM / 256), 1024, 0, stream>>>(   // 1152 blocks (%8==0)
      Xb, W1t, b1, cnt, expoff, toff, bucket, hmid, nullptr);
  moe_gemm<2><<<MAXT * (D_DIM / 256) * 2, 1024, 0, stream>>>( // 576 blocks (%8==0)
      hmid, W2t, b2, cnt, expoff, toff, bucket, ybufA, ybufB);
  combine_kernel<<<N_TOK, 256, 0, stream>>>(ybufA, ybufB, pairw, pairslot, out);
}